// Round 1
// baseline (430.120 us; speedup 1.0000x reference)
//
#include <hip/hip_runtime.h>
#include <hip/hip_bf16.h>
#include <cstdint>

#define BB  32
#define CC  512
#define NN  1024
#define HH  8
#define DHH 64
#define KR  256

using f32x4  = __attribute__((ext_vector_type(4))) float;
using bf16x8 = __attribute__((ext_vector_type(8))) __bf16;

__device__ __forceinline__ unsigned short f2bf(float f) {
  unsigned int u = __float_as_uint(f);
  u += 0x7fffu + ((u >> 16) & 1u);          // round-to-nearest-even
  return (unsigned short)(u >> 16);
}

// ---------------------------------------------------------------------------
// Transpose + convert f32 -> bf16:  dst[c][r] = bf16(src[r][c])
// ---------------------------------------------------------------------------
__global__ void transcvt_kernel(const float* __restrict__ src,
                                unsigned short* __restrict__ dst,
                                int R, int Cc) {
  int idx = blockIdx.x * 256 + threadIdx.x;
  if (idx < R * Cc) {
    int r = idx / Cc, c = idx % Cc;
    dst[(size_t)c * R + r] = f2bf(src[idx]);
  }
}

// ---------------------------------------------------------------------------
// xf = transpose(x) + pos ; y = relu(LN(xf))   -> y bf16 [B*N][C]
// block: 256 threads handles (b, 16 tokens)
// ---------------------------------------------------------------------------
__global__ __launch_bounds__(256) void ln_relu_kernel(
    const float* __restrict__ x, const float* __restrict__ pos,
    const float* __restrict__ g, const float* __restrict__ bta,
    unsigned short* __restrict__ y) {
  __shared__ float tile[16][516];     // padded: 2-way banks
  __shared__ float smu[16], srs[16];
  const int b = blockIdx.y, n0 = blockIdx.x * 16;
  const int tid = threadIdx.x;
  const float* xb = x + (size_t)b * CC * NN;

  // load x[b][c][n0+nl] transposed into LDS
  #pragma unroll
  for (int i = 0; i < 32; ++i) {
    int e = i * 256 + tid;
    int c = e >> 4, nl = e & 15;
    tile[nl][c] = xb[(size_t)c * NN + n0 + nl];
  }
  __syncthreads();

  // stats: 16 threads per token row
  const int r = tid >> 4, l16 = tid & 15;
  float s = 0.f, s2 = 0.f;
  #pragma unroll
  for (int i = 0; i < 32; ++i) {
    int c = l16 + i * 16;
    float v = tile[r][c] + pos[(size_t)(n0 + r) * CC + c];
    s += v; s2 += v * v;
  }
  #pragma unroll
  for (int d = 1; d < 16; d <<= 1) { s += __shfl_xor(s, d); s2 += __shfl_xor(s2, d); }
  if (l16 == 0) {
    float mu = s * (1.f / 512.f);
    float var = s2 * (1.f / 512.f) - mu * mu;
    smu[r] = mu;
    srs[r] = rsqrtf(var + 1e-5f);
  }
  __syncthreads();

  unsigned short* yb = y + ((size_t)b * NN + n0) * CC;
  for (int rr = 0; rr < 16; ++rr) {
    float mu = smu[rr], rs = srs[rr];
    #pragma unroll
    for (int c = tid; c < CC; c += 256) {
      float v = tile[rr][c] + pos[(size_t)(n0 + rr) * CC + c];
      float o = (v - mu) * rs * g[c] + bta[c];
      o = o > 0.f ? o : 0.f;
      yb[(size_t)rr * CC + c] = f2bf(o);
    }
  }
}

// ---------------------------------------------------------------------------
// TN GEMM: C[M,N] = A[M,K] * Bt[N,K]^T, bf16 in, f32 acc.
// 128x128 tile, 4 waves (2x2), each wave 64x64 (4x4 frags of 16x16x32 MFMA).
// MODE 0: bf16 store C[r*Nn+col] (+ z*strideC)
// MODE 1: bf16 transposed store dst[(r/TB)*batchStride + col*TB + r%TB]
// MODE 2: f32 store out[b][col][tok] = acc + bias[col] + x[b][col][tok] + pos[tok][col]
// ---------------------------------------------------------------------------
template <int MODE>
__global__ __launch_bounds__(256) void gemm_tn(
    const unsigned short* __restrict__ A, int lda, long long strideA,
    const unsigned short* __restrict__ Bt, int ldb, long long strideB,
    unsigned short* __restrict__ Cb, long long strideC,
    int Nn, int Kk, int TB, long long batchStride,
    const float* __restrict__ xres, const float* __restrict__ posres,
    const float* __restrict__ bias, float* __restrict__ outF) {
  __shared__ unsigned short aT[128][72];   // 144B row stride: aligned + 2-way banks
  __shared__ unsigned short bT[128][72];
  const int mb = blockIdx.x * 128, nb = blockIdx.y * 128, z = blockIdx.z;
  A  += (size_t)strideA * z;
  Bt += (size_t)strideB * z;
  if (MODE == 0 || MODE == 1) Cb += (size_t)strideC * z;
  const int tid  = threadIdx.x;
  const int lane = tid & 63;
  const int wave = tid >> 6;
  const int wm = (wave >> 1) * 64, wn = (wave & 1) * 64;
  const int lr = tid >> 2;          // 0..63
  const int lk = (tid & 3) * 8;     // 0,8,16,24
  f32x4 acc[4][4] = {};

  for (int k0 = 0; k0 < Kk; k0 += 32) {
    __syncthreads();
    *reinterpret_cast<uint4*>(&aT[lr][lk]) =
        *reinterpret_cast<const uint4*>(&A[(size_t)(mb + lr) * lda + k0 + lk]);
    *reinterpret_cast<uint4*>(&aT[lr + 64][lk]) =
        *reinterpret_cast<const uint4*>(&A[(size_t)(mb + lr + 64) * lda + k0 + lk]);
    *reinterpret_cast<uint4*>(&bT[lr][lk]) =
        *reinterpret_cast<const uint4*>(&Bt[(size_t)(nb + lr) * ldb + k0 + lk]);
    *reinterpret_cast<uint4*>(&bT[lr + 64][lk]) =
        *reinterpret_cast<const uint4*>(&Bt[(size_t)(nb + lr + 64) * ldb + k0 + lk]);
    __syncthreads();
    bf16x8 af[4], bfv[4];
    #pragma unroll
    for (int i = 0; i < 4; ++i)
      af[i] = *reinterpret_cast<const bf16x8*>(&aT[wm + i * 16 + (lane & 15)][(lane >> 4) * 8]);
    #pragma unroll
    for (int i = 0; i < 4; ++i)
      bfv[i] = *reinterpret_cast<const bf16x8*>(&bT[wn + i * 16 + (lane & 15)][(lane >> 4) * 8]);
    #pragma unroll
    for (int i = 0; i < 4; ++i)
      #pragma unroll
      for (int j = 0; j < 4; ++j)
        acc[i][j] = __builtin_amdgcn_mfma_f32_16x16x32_bf16(af[i], bfv[j], acc[i][j], 0, 0, 0);
  }

  #pragma unroll
  for (int i = 0; i < 4; ++i) {
    const int r0 = mb + wm + i * 16 + ((lane >> 4) << 2);
    #pragma unroll
    for (int j = 0; j < 4; ++j) {
      const int col = nb + wn + j * 16 + (lane & 15);
      if (MODE == 0) {
        #pragma unroll
        for (int t = 0; t < 4; ++t)
          Cb[(size_t)(r0 + t) * Nn + col] = f2bf(acc[i][j][t]);
      } else if (MODE == 1) {
        unsigned int lo = (unsigned int)f2bf(acc[i][j][0]) | ((unsigned int)f2bf(acc[i][j][1]) << 16);
        unsigned int hi = (unsigned int)f2bf(acc[i][j][2]) | ((unsigned int)f2bf(acc[i][j][3]) << 16);
        size_t addr = (size_t)(r0 / TB) * batchStride + (size_t)col * TB + (r0 % TB);
        uint2 u; u.x = lo; u.y = hi;
        *reinterpret_cast<uint2*>(&Cb[addr]) = u;
      } else {
        const int bb = r0 >> 10, t0 = r0 & 1023;
        const size_t base = ((size_t)bb * CC + col) * NN + t0;
        float4 xv = *reinterpret_cast<const float4*>(&xres[base]);
        float bcol = bias[col];
        float4 ov;
        ov.x = acc[i][j][0] + bcol + xv.x + posres[(size_t)(t0 + 0) * CC + col];
        ov.y = acc[i][j][1] + bcol + xv.y + posres[(size_t)(t0 + 1) * CC + col];
        ov.z = acc[i][j][2] + bcol + xv.z + posres[(size_t)(t0 + 2) * CC + col];
        ov.w = acc[i][j][3] + bcol + xv.w + posres[(size_t)(t0 + 3) * CC + col];
        *reinterpret_cast<float4*>(&outF[base]) = ov;
      }
    }
  }
}

// ---------------------------------------------------------------------------
// Attention: per block (b, h, 64 tokens); each wave owns 16 tokens.
// QK^T (M=16,N=256,K=64) -> exact softmax -> P via LDS -> PV (M=16,N=64,K=256)
// ---------------------------------------------------------------------------
__global__ __launch_bounds__(256) void attn_kernel(
    const unsigned short* __restrict__ q,    // [B*N][C]
    const unsigned short* __restrict__ kB,   // [B][KR][C]
    const unsigned short* __restrict__ vT,   // [B][C][KR]
    unsigned short* __restrict__ O) {        // [B*N][C]
  __shared__ unsigned short P[4][16][264];   // per-wave P tile, padded
  const int b = blockIdx.z, h = blockIdx.y;
  const int wave = threadIdx.x >> 6, lane = threadIdx.x & 63;
  const int tokb = blockIdx.x * 64 + wave * 16;
  const unsigned short* qh = q  + ((size_t)b * NN + tokb) * CC + h * DHH;
  const unsigned short* kh = kB + ((size_t)b * KR) * CC + h * DHH;
  const unsigned short* vh = vT + ((size_t)b * CC + h * DHH) * KR;

  f32x4 s[16] = {};
  bf16x8 aq[2];
  #pragma unroll
  for (int ks = 0; ks < 2; ++ks)
    aq[ks] = *reinterpret_cast<const bf16x8*>(
        &qh[(size_t)(lane & 15) * CC + ks * 32 + (lane >> 4) * 8]);
  #pragma unroll
  for (int ni = 0; ni < 16; ++ni) {
    #pragma unroll
    for (int ks = 0; ks < 2; ++ks) {
      bf16x8 bk = *reinterpret_cast<const bf16x8*>(
          &kh[(size_t)(ni * 16 + (lane & 15)) * CC + ks * 32 + (lane >> 4) * 8]);
      s[ni] = __builtin_amdgcn_mfma_f32_16x16x32_bf16(aq[ks], bk, s[ni], 0, 0, 0);
    }
  }

  // softmax over kk=256; lane holds rows (lane>>4)*4+j, cols ni*16+(lane&15)
  float mrow[4], lsum[4];
  #pragma unroll
  for (int j = 0; j < 4; ++j) {
    float m = -1e30f;
    #pragma unroll
    for (int ni = 0; ni < 16; ++ni) m = fmaxf(m, s[ni][j]);
    #pragma unroll
    for (int d = 1; d < 16; d <<= 1) m = fmaxf(m, __shfl_xor(m, d));
    mrow[j] = m;
    lsum[j] = 0.f;
  }
  #pragma unroll
  for (int ni = 0; ni < 16; ++ni) {
    #pragma unroll
    for (int j = 0; j < 4; ++j) {
      float p = __expf((s[ni][j] - mrow[j]) * 0.125f);
      lsum[j] += p;
      P[wave][(lane >> 4) * 4 + j][ni * 16 + (lane & 15)] = f2bf(p);
    }
  }
  #pragma unroll
  for (int j = 0; j < 4; ++j)
    #pragma unroll
    for (int d = 1; d < 16; d <<= 1) lsum[j] += __shfl_xor(lsum[j], d);
  __syncthreads();

  f32x4 o[4] = {};
  #pragma unroll
  for (int ks = 0; ks < 8; ++ks) {
    bf16x8 ap = *reinterpret_cast<const bf16x8*>(
        &P[wave][lane & 15][ks * 32 + (lane >> 4) * 8]);
    #pragma unroll
    for (int ni = 0; ni < 4; ++ni) {
      bf16x8 bv = *reinterpret_cast<const bf16x8*>(
          &vh[(size_t)(ni * 16 + (lane & 15)) * KR + ks * 32 + (lane >> 4) * 8]);
      o[ni] = __builtin_amdgcn_mfma_f32_16x16x32_bf16(ap, bv, o[ni], 0, 0, 0);
    }
  }

  unsigned short* Ob = O + ((size_t)b * NN + tokb) * CC + h * DHH;
  #pragma unroll
  for (int ni = 0; ni < 4; ++ni)
    #pragma unroll
    for (int j = 0; j < 4; ++j) {
      int row = (lane >> 4) * 4 + j;
      int col = ni * 16 + (lane & 15);
      Ob[(size_t)row * CC + col] = f2bf(o[ni][j] / lsum[j]);
    }
}

// ---------------------------------------------------------------------------
extern "C" void kernel_launch(void* const* d_in, const int* in_sizes, int n_in,
                              void* d_out, int out_size, void* d_ws, size_t ws_size,
                              hipStream_t stream) {
  const float* x    = (const float*)d_in[0];
  const float* pos  = (const float*)d_in[1];
  const float* ln_g = (const float*)d_in[2];
  const float* ln_b = (const float*)d_in[3];
  const float* Wq   = (const float*)d_in[4];
  const float* Wk   = (const float*)d_in[5];
  const float* Wv   = (const float*)d_in[6];
  const float* pk   = (const float*)d_in[7];
  const float* pv   = (const float*)d_in[8];
  const float* Wo   = (const float*)d_in[9];
  const float* bo   = (const float*)d_in[10];
  float* out = (float*)d_out;

  unsigned short* ws = (unsigned short*)d_ws;
  size_t off = 0;
  auto alloc = [&](size_t elems) { unsigned short* p = ws + off; off += elems; return p; };
  unsigned short* WqT  = alloc(512 * 512);
  unsigned short* WkT  = alloc(512 * 512);
  unsigned short* WvT  = alloc(512 * 512);
  unsigned short* WoT  = alloc(512 * 512);
  unsigned short* pkT  = alloc(1024 * 256);
  unsigned short* pvT  = alloc(1024 * 256);
  unsigned short* yB   = alloc((size_t)32768 * 512);
  unsigned short* qB   = alloc((size_t)32768 * 512);
  unsigned short* yWkT = alloc((size_t)32 * 512 * 1024);
  unsigned short* yWvT = alloc((size_t)32 * 512 * 1024);
  unsigned short* kBuf = alloc((size_t)32 * 256 * 512);
  unsigned short* vTB  = alloc((size_t)32 * 512 * 256);
  unsigned short* OB   = alloc((size_t)32768 * 512);

  // weight prep (transpose to [out][in] / [rank][n], cvt bf16)
  transcvt_kernel<<<1024, 256, 0, stream>>>(Wq, WqT, 512, 512);
  transcvt_kernel<<<1024, 256, 0, stream>>>(Wk, WkT, 512, 512);
  transcvt_kernel<<<1024, 256, 0, stream>>>(Wv, WvT, 512, 512);
  transcvt_kernel<<<1024, 256, 0, stream>>>(Wo, WoT, 512, 512);
  transcvt_kernel<<<1024, 256, 0, stream>>>(pk, pkT, 1024, 256);
  transcvt_kernel<<<1024, 256, 0, stream>>>(pv, pvT, 1024, 256);

  // LN + ReLU -> y bf16
  ln_relu_kernel<<<dim3(64, 32), 256, 0, stream>>>(x, pos, ln_g, ln_b, yB);

  // GEMM1: q = y@Wq (normal); yWk,yWv stored transposed per batch [b][d][tok]
  dim3 g1(256, 4, 1);
  gemm_tn<0><<<g1, 256, 0, stream>>>(yB, 512, 0, WqT, 512, 0, qB, 0,
                                     512, 512, 0, 0, nullptr, nullptr, nullptr, nullptr);
  gemm_tn<1><<<g1, 256, 0, stream>>>(yB, 512, 0, WkT, 512, 0, yWkT, 0,
                                     512, 512, 1024, (long long)512 * 1024,
                                     nullptr, nullptr, nullptr, nullptr);
  gemm_tn<1><<<g1, 256, 0, stream>>>(yB, 512, 0, WvT, 512, 0, yWvT, 0,
                                     512, 512, 1024, (long long)512 * 1024,
                                     nullptr, nullptr, nullptr, nullptr);

  // GEMM2 (batched over b): k_ = projk^T @ yWk ; v^T stored [b][d][kk]
  dim3 g2(2, 4, 32);
  gemm_tn<0><<<g2, 256, 0, stream>>>(pkT, 1024, 0, yWkT, 1024, (long long)512 * 1024,
                                     kBuf, (long long)256 * 512,
                                     512, 1024, 0, 0, nullptr, nullptr, nullptr, nullptr);
  gemm_tn<1><<<g2, 256, 0, stream>>>(pvT, 1024, 0, yWvT, 1024, (long long)512 * 1024,
                                     vTB, (long long)512 * 256,
                                     512, 1024, 256, (long long)512 * 256,
                                     nullptr, nullptr, nullptr, nullptr);

  // attention
  attn_kernel<<<dim3(16, 8, 32), 256, 0, stream>>>(qB, kBuf, vTB, OB);

  // GEMM5: out = O@Wo + bo + (x + pos), stored transposed [b][c][tok] f32
  gemm_tn<2><<<g1, 256, 0, stream>>>(OB, 512, 0, WoT, 512, 0, nullptr, 0,
                                     512, 512, 0, 0, x, pos, bo, out);
}

// Round 2
// 310.236 us; speedup vs baseline: 1.3864x; 1.3864x over previous
//
#include <hip/hip_runtime.h>
#include <hip/hip_bf16.h>
#include <cstdint>

#define BB  32
#define CC  512
#define NN  1024
#define HH  8
#define DHH 64
#define KR  256

using f32x4  = __attribute__((ext_vector_type(4))) float;
using f32x16 = __attribute__((ext_vector_type(16))) float;
using bf16x8 = __attribute__((ext_vector_type(8))) __bf16;
using u32x4  = __attribute__((ext_vector_type(4))) unsigned int;

__device__ __forceinline__ unsigned short f2bf(float f) {
  unsigned int u = __float_as_uint(f);
  u += 0x7fffu + ((u >> 16) & 1u);          // RNE
  return (unsigned short)(u >> 16);
}

__device__ __forceinline__ unsigned int pknat(float a, float b) {
  unsigned short ua = __builtin_bit_cast(unsigned short, (__bf16)a);
  unsigned short ub = __builtin_bit_cast(unsigned short, (__bf16)b);
  return (unsigned int)ua | ((unsigned int)ub << 16);
}

// async global->LDS, 16B per lane; LDS dest must be wave-uniform base
__device__ __forceinline__ void gload16(const void* gsrc, void* ldst) {
  __builtin_amdgcn_global_load_lds(
      (const __attribute__((address_space(1))) unsigned int*)gsrc,
      (__attribute__((address_space(3))) unsigned int*)ldst, 16, 0, 0);
}

// ---------------------------------------------------------------------------
// Fused transpose+cvt of the 6 weight matrices: dst[c][r] = bf16(src[r][c])
// ---------------------------------------------------------------------------
__global__ __launch_bounds__(256) void transcvt_all(
    const float* __restrict__ w0, const float* __restrict__ w1,
    const float* __restrict__ w2, const float* __restrict__ w3,
    const float* __restrict__ p0, const float* __restrict__ p1,
    unsigned short* __restrict__ d0, unsigned short* __restrict__ d1,
    unsigned short* __restrict__ d2, unsigned short* __restrict__ d3,
    unsigned short* __restrict__ e0, unsigned short* __restrict__ e1) {
  const int m = blockIdx.y;
  const float* src = m==0?w0:m==1?w1:m==2?w2:m==3?w3:m==4?p0:p1;
  unsigned short* dst = m==0?d0:m==1?d1:m==2?d2:m==3?d3:m==4?e0:e1;
  const int R = (m < 4) ? 512 : 1024;
  const int logC = (m < 4) ? 9 : 8;
  int idx = blockIdx.x * 256 + threadIdx.x;
  int r = idx >> logC, c = idx & ((1 << logC) - 1);
  dst[(size_t)c * R + r] = f2bf(src[idx]);
}

// ---------------------------------------------------------------------------
// xf = transpose(x) + pos ; y = relu(LN(xf))   -> y bf16 [B*N][C]
// ---------------------------------------------------------------------------
__global__ __launch_bounds__(256) void ln_relu_kernel(
    const float* __restrict__ x, const float* __restrict__ pos,
    const float* __restrict__ g, const float* __restrict__ bta,
    unsigned short* __restrict__ y) {
  __shared__ float tile[16][516];
  __shared__ float smu[16], srs[16];
  const int b = blockIdx.y, n0 = blockIdx.x * 16;
  const int tid = threadIdx.x;
  const float* xb = x + (size_t)b * CC * NN;

  #pragma unroll
  for (int i = 0; i < 32; ++i) {
    int e = i * 256 + tid;
    int c = e >> 4, nl = e & 15;
    tile[nl][c] = xb[(size_t)c * NN + n0 + nl];
  }
  __syncthreads();

  const int r = tid >> 4, l16 = tid & 15;
  float s = 0.f, s2 = 0.f;
  #pragma unroll
  for (int i = 0; i < 32; ++i) {
    int c = l16 + i * 16;
    float v = tile[r][c] + pos[(size_t)(n0 + r) * CC + c];
    s += v; s2 += v * v;
  }
  #pragma unroll
  for (int d = 1; d < 16; d <<= 1) { s += __shfl_xor(s, d); s2 += __shfl_xor(s2, d); }
  if (l16 == 0) {
    float mu = s * (1.f / 512.f);
    float var = s2 * (1.f / 512.f) - mu * mu;
    smu[r] = mu;
    srs[r] = rsqrtf(var + 1e-5f);
  }
  __syncthreads();

  unsigned short* yb = y + ((size_t)b * NN + n0) * CC;
  for (int rr = 0; rr < 16; ++rr) {
    float mu = smu[rr], rs = srs[rr];
    #pragma unroll
    for (int c = tid; c < CC; c += 256) {
      float v = tile[rr][c] + pos[(size_t)(n0 + rr) * CC + c];
      float o = (v - mu) * rs * g[c] + bta[c];
      o = o > 0.f ? o : 0.f;
      yb[(size_t)rr * CC + c] = f2bf(o);
    }
  }
}

// ---------------------------------------------------------------------------
// TN GEMM, m97 structure: linear [128][32] LDS tiles, global_load_lds x16.
// MODE 0: bf16 store; MODE 1: bf16 transposed store; MODE 2: f32 fused epilogue
// ---------------------------------------------------------------------------
template <int MODE>
__global__ __launch_bounds__(256) void gemm_tn(
    const unsigned short* __restrict__ A, int lda, long long strideA,
    const unsigned short* __restrict__ Bt, int ldb, long long strideB,
    unsigned short* __restrict__ Cb, long long strideC,
    int Nn, int Kk, int TB, long long batchStride,
    const float* __restrict__ xres, const float* __restrict__ posres,
    const float* __restrict__ bias, float* __restrict__ outF) {
  __shared__ __align__(16) unsigned short aL[128 * 32];
  __shared__ __align__(16) unsigned short bL[128 * 32];
  const int mb = blockIdx.x * 128, nb = blockIdx.y * 128, z = blockIdx.z;
  A  += (size_t)strideA * z;
  Bt += (size_t)strideB * z;
  if (MODE == 0 || MODE == 1) Cb += (size_t)strideC * z;
  const int tid  = threadIdx.x;
  const int lane = tid & 63;
  const int wave = tid >> 6;
  const int wm = (wave >> 1) * 64, wn = (wave & 1) * 64;
  const int srow = lane >> 2;          // staging: row-in-16 group
  const int schk = (lane & 3) * 8;     // 16B chunk
  f32x4 acc[4][4] = {};

  for (int k0 = 0; k0 < Kk; k0 += 32) {
    __syncthreads();
    #pragma unroll
    for (int i = 0; i < 2; ++i) {
      int r = wave * 32 + i * 16;
      gload16(&A [(size_t)(mb + r + srow) * lda + k0 + schk], &aL[r * 32]);
      gload16(&Bt[(size_t)(nb + r + srow) * ldb + k0 + schk], &bL[r * 32]);
    }
    __syncthreads();
    bf16x8 af[4], bfv[4];
    #pragma unroll
    for (int i = 0; i < 4; ++i)
      af[i] = *reinterpret_cast<const bf16x8*>(&aL[(wm + i * 16 + (lane & 15)) * 32 + (lane >> 4) * 8]);
    #pragma unroll
    for (int i = 0; i < 4; ++i)
      bfv[i] = *reinterpret_cast<const bf16x8*>(&bL[(wn + i * 16 + (lane & 15)) * 32 + (lane >> 4) * 8]);
    #pragma unroll
    for (int i = 0; i < 4; ++i)
      #pragma unroll
      for (int j = 0; j < 4; ++j)
        acc[i][j] = __builtin_amdgcn_mfma_f32_16x16x32_bf16(af[i], bfv[j], acc[i][j], 0, 0, 0);
  }

  #pragma unroll
  for (int i = 0; i < 4; ++i) {
    const int r0 = mb + wm + i * 16 + ((lane >> 4) << 2);
    #pragma unroll
    for (int j = 0; j < 4; ++j) {
      const int col = nb + wn + j * 16 + (lane & 15);
      if (MODE == 0) {
        #pragma unroll
        for (int t = 0; t < 4; ++t)
          Cb[(size_t)(r0 + t) * Nn + col] = f2bf(acc[i][j][t]);
      } else if (MODE == 1) {
        unsigned int lo = (unsigned int)f2bf(acc[i][j][0]) | ((unsigned int)f2bf(acc[i][j][1]) << 16);
        unsigned int hi = (unsigned int)f2bf(acc[i][j][2]) | ((unsigned int)f2bf(acc[i][j][3]) << 16);
        size_t addr = (size_t)(r0 / TB) * batchStride + (size_t)col * TB + (r0 % TB);
        uint2 u; u.x = lo; u.y = hi;
        *reinterpret_cast<uint2*>(&Cb[addr]) = u;
      } else {
        const int bb = r0 >> 10, t0 = r0 & 1023;
        const size_t base = ((size_t)bb * CC + col) * NN + t0;
        float4 xv = *reinterpret_cast<const float4*>(&xres[base]);
        float bcol = bias[col];
        float4 ov;
        ov.x = acc[i][j][0] + bcol + xv.x + posres[(size_t)(t0 + 0) * CC + col];
        ov.y = acc[i][j][1] + bcol + xv.y + posres[(size_t)(t0 + 1) * CC + col];
        ov.z = acc[i][j][2] + bcol + xv.z + posres[(size_t)(t0 + 2) * CC + col];
        ov.w = acc[i][j][3] + bcol + xv.w + posres[(size_t)(t0 + 3) * CC + col];
        *reinterpret_cast<float4*>(&outF[base]) = ov;
      }
    }
  }
}

// ---------------------------------------------------------------------------
// Attention, 32x32x16 MFMA, swapped QK^T, in-register softmax.
// Block = (b, h, 128 tokens), 4 waves x 32 tokens. K,V staged in LDS
// (global_load_lds, source pre-swizzled; reads XOR-swizzled: chunk ^= row&7).
// ---------------------------------------------------------------------------
__global__ __launch_bounds__(256, 2) void attn_kernel(
    const unsigned short* __restrict__ q,    // [B*N][C]
    const unsigned short* __restrict__ kB,   // [B][KR][C]
    const unsigned short* __restrict__ vT,   // [B][C][KR]
    unsigned short* __restrict__ O) {        // [B*N][C]
  __shared__ __align__(16) unsigned short smem[32768]; // K [256][64] @0, V [64][256] @16384
  const int wgid = blockIdx.x;
  const int grp  = wgid & 255;       // (b,h): keeps all token-groups of (b,h) on one XCD
  const int tg   = wgid >> 8;
  const int h = grp & 7, b = grp >> 3;
  const int wave = threadIdx.x >> 6, lane = threadIdx.x & 63;
  const int t32 = lane & 31, g2 = lane >> 5;
  const int tokb = tg * 128 + wave * 32;

  // Q fragments (B-operand): col = token, k-slot(g2,e) = st*16 + g2*8 + e
  const unsigned short* qp = q + ((size_t)(b * NN + tokb + t32)) * CC + h * DHH + g2 * 8;
  bf16x8 qf[4];
  #pragma unroll
  for (int st = 0; st < 4; ++st)
    qf[st] = *reinterpret_cast<const bf16x8*>(qp + (size_t)st * 16);

  // stage K: lds linear chunk c of row holds global chunk c ^ (row&7)
  {
    const unsigned short* kb = kB + ((size_t)b * KR) * CC + h * DHH;
    const int r0w = wave * 64;
    #pragma unroll
    for (int i = 0; i < 8; ++i) {
      int row = r0w + i * 8 + (lane >> 3);
      int sc  = (lane & 7) ^ (row & 7);
      gload16(kb + (size_t)row * CC + sc * 8, &smem[(r0w + i * 8) * 64]);
    }
    const unsigned short* vb = vT + ((size_t)b * CC + h * DHH) * KR;
    const int v0w = wave * 16;
    #pragma unroll
    for (int i = 0; i < 8; ++i) {
      int row = v0w + i * 2 + (lane >> 5);
      int sc  = (lane & 31) ^ (row & 7);
      gload16(vb + (size_t)row * KR + sc * 8, &smem[16384 + (v0w + i * 2) * 256]);
    }
  }
  __syncthreads();

  // QK^T swapped: S'[kk][tok] = sum_d K[kk][d] Q[tok][d]
  f32x16 s8[8] = {};
  #pragma unroll
  for (int t8 = 0; t8 < 8; ++t8) {
    const int row = t8 * 32 + t32;
    #pragma unroll
    for (int st = 0; st < 4; ++st) {
      int ch = (2 * st + g2) ^ (row & 7);
      bf16x8 kf = *reinterpret_cast<const bf16x8*>(&smem[row * 64 + ch * 8]);
      s8[t8] = __builtin_amdgcn_mfma_f32_32x32x16_bf16(kf, qf[st], s8[t8], 0, 0, 0);
    }
  }

  // softmax over kk: lane holds 128 of 256 values for token t32; partner lane^32 rest
  float m = -1e30f;
  #pragma unroll
  for (int t8 = 0; t8 < 8; ++t8)
    #pragma unroll
    for (int r = 0; r < 16; ++r) m = fmaxf(m, s8[t8][r]);
  m = fmaxf(m, __shfl_xor(m, 32));
  const float cexp = 0.125f * 1.44269504088896f;   // scale * log2(e)
  float ls = 0.f;
  #pragma unroll
  for (int t8 = 0; t8 < 8; ++t8)
    #pragma unroll
    for (int r = 0; r < 16; ++r) {
      float p = __builtin_amdgcn_exp2f((s8[t8][r] - m) * cexp);
      s8[t8][r] = p;
      ls += p;
    }
  ls += __shfl_xor(ls, 32);
  float rinv = __builtin_amdgcn_rcpf(ls);

  // PV: pack P->bf16 A-frags via half-exchange with lane^32; V from LDS
  f32x16 o0 = {}, o1 = {};
  #pragma unroll
  for (int t8 = 0; t8 < 8; ++t8) {
    unsigned int pkd[8];
    #pragma unroll
    for (int qq = 0; qq < 4; ++qq) {
      pkd[qq * 2 + 0] = pknat(s8[t8][4 * qq + 0], s8[t8][4 * qq + 1]);
      pkd[qq * 2 + 1] = pknat(s8[t8][4 * qq + 2], s8[t8][4 * qq + 3]);
    }
    #pragma unroll
    for (int a = 0; a < 2; ++a) {
      const int ks = t8 * 2 + a;
      unsigned int xe0 = pkd[4 * a + 0], xe1 = pkd[4 * a + 1];
      unsigned int xo0 = pkd[4 * a + 2], xo1 = pkd[4 * a + 3];
      // pa dword r covers kk = 16ks + 8g2 + 2r..+1
      unsigned int d0 = g2 ? __shfl_xor(xo0, 32) : xe0;
      unsigned int d1 = g2 ? __shfl_xor(xo1, 32) : xe1;
      unsigned int d2 = g2 ? xo0 : __shfl_xor(xe0, 32);
      unsigned int d3 = g2 ? xo1 : __shfl_xor(xe1, 32);
      u32x4 pv_ = {d0, d1, d2, d3};
      bf16x8 pa = __builtin_bit_cast(bf16x8, pv_);
      #pragma unroll
      for (int dt = 0; dt < 2; ++dt) {
        int row = dt * 32 + t32;
        int ch = (2 * ks + g2) ^ (row & 7);
        bf16x8 bv = *reinterpret_cast<const bf16x8*>(&smem[16384 + row * 256 + ch * 8]);
        if (dt == 0) o0 = __builtin_amdgcn_mfma_f32_32x32x16_bf16(pa, bv, o0, 0, 0, 0);
        else         o1 = __builtin_amdgcn_mfma_f32_32x32x16_bf16(pa, bv, o1, 0, 0, 0);
      }
    }
  }

  // epilogue: O[tok][d] / lsum(tok)
  unsigned short* Ob = O + ((size_t)(b * NN + tokb)) * CC + h * DHH;
  #pragma unroll
  for (int r = 0; r < 16; ++r) {
    int tl = (r & 3) + 8 * (r >> 2) + 4 * g2;
    float rs = __shfl(rinv, tl);
    Ob[(size_t)tl * CC + t32]      = f2bf(o0[r] * rs);
    Ob[(size_t)tl * CC + 32 + t32] = f2bf(o1[r] * rs);
  }
}

// ---------------------------------------------------------------------------
extern "C" void kernel_launch(void* const* d_in, const int* in_sizes, int n_in,
                              void* d_out, int out_size, void* d_ws, size_t ws_size,
                              hipStream_t stream) {
  const float* x    = (const float*)d_in[0];
  const float* pos  = (const float*)d_in[1];
  const float* ln_g = (const float*)d_in[2];
  const float* ln_b = (const float*)d_in[3];
  const float* Wq   = (const float*)d_in[4];
  const float* Wk   = (const float*)d_in[5];
  const float* Wv   = (const float*)d_in[6];
  const float* pk   = (const float*)d_in[7];
  const float* pv   = (const float*)d_in[8];
  const float* Wo   = (const float*)d_in[9];
  const float* bo   = (const float*)d_in[10];
  float* out = (float*)d_out;

  unsigned short* ws = (unsigned short*)d_ws;
  size_t off = 0;
  auto alloc = [&](size_t elems) { unsigned short* p = ws + off; off += elems; return p; };
  unsigned short* WqT  = alloc(512 * 512);
  unsigned short* WkT  = alloc(512 * 512);
  unsigned short* WvT  = alloc(512 * 512);
  unsigned short* WoT  = alloc(512 * 512);
  unsigned short* pkT  = alloc(1024 * 256);
  unsigned short* pvT  = alloc(1024 * 256);
  unsigned short* yB   = alloc((size_t)32768 * 512);
  unsigned short* qB   = alloc((size_t)32768 * 512);
  unsigned short* yWkT = alloc((size_t)32 * 512 * 1024);
  unsigned short* yWvT = alloc((size_t)32 * 512 * 1024);
  unsigned short* kBuf = alloc((size_t)32 * 256 * 512);
  unsigned short* vTB  = alloc((size_t)32 * 512 * 256);
  unsigned short* OB   = alloc((size_t)32768 * 512);

  transcvt_all<<<dim3(1024, 6), 256, 0, stream>>>(Wq, Wk, Wv, Wo, pk, pv,
                                                  WqT, WkT, WvT, WoT, pkT, pvT);

  ln_relu_kernel<<<dim3(64, 32), 256, 0, stream>>>(x, pos, ln_g, ln_b, yB);

  dim3 g1(256, 4, 1);
  gemm_tn<0><<<g1, 256, 0, stream>>>(yB, 512, 0, WqT, 512, 0, qB, 0,
                                     512, 512, 0, 0, nullptr, nullptr, nullptr, nullptr);
  gemm_tn<1><<<g1, 256, 0, stream>>>(yB, 512, 0, WkT, 512, 0, yWkT, 0,
                                     512, 512, 1024, (long long)512 * 1024,
                                     nullptr, nullptr, nullptr, nullptr);
  gemm_tn<1><<<g1, 256, 0, stream>>>(yB, 512, 0, WvT, 512, 0, yWvT, 0,
                                     512, 512, 1024, (long long)512 * 1024,
                                     nullptr, nullptr, nullptr, nullptr);

  dim3 g2(2, 4, 32);
  gemm_tn<0><<<g2, 256, 0, stream>>>(pkT, 1024, 0, yWkT, 1024, (long long)512 * 1024,
                                     kBuf, (long long)256 * 512,
                                     512, 1024, 0, 0, nullptr, nullptr, nullptr, nullptr);
  gemm_tn<1><<<g2, 256, 0, stream>>>(pvT, 1024, 0, yWvT, 1024, (long long)512 * 1024,
                                     vTB, (long long)512 * 256,
                                     512, 1024, 256, (long long)512 * 256,
                                     nullptr, nullptr, nullptr, nullptr);

  attn_kernel<<<dim3(2048, 1, 1), 256, 0, stream>>>(qB, kBuf, vTB, OB);

  gemm_tn<2><<<g1, 256, 0, stream>>>(OB, 512, 0, WoT, 512, 0, nullptr, 0,
                                     512, 512, 0, 0, x, pos, bo, out);
}

// Round 3
// 228.559 us; speedup vs baseline: 1.8819x; 1.3574x over previous
//
#include <hip/hip_runtime.h>
#include <hip/hip_bf16.h>
#include <cstdint>

#define BB  32
#define CC  512
#define NN  1024
#define HH  8
#define DHH 64
#define KR  256

using f32x4  = __attribute__((ext_vector_type(4))) float;
using f32x16 = __attribute__((ext_vector_type(16))) float;
using bf16x8 = __attribute__((ext_vector_type(8))) __bf16;
using u32x4  = __attribute__((ext_vector_type(4))) unsigned int;

__device__ __forceinline__ unsigned short f2bf(float f) {
  unsigned int u = __float_as_uint(f);
  u += 0x7fffu + ((u >> 16) & 1u);          // RNE
  return (unsigned short)(u >> 16);
}

__device__ __forceinline__ unsigned int pknat(float a, float b) {
  unsigned short ua = __builtin_bit_cast(unsigned short, (__bf16)a);
  unsigned short ub = __builtin_bit_cast(unsigned short, (__bf16)b);
  return (unsigned int)ua | ((unsigned int)ub << 16);
}

// async global->LDS, 16B/lane; LDS dest wave-uniform base + lane*16
__device__ __forceinline__ void gload16(const void* gsrc, void* ldst) {
  __builtin_amdgcn_global_load_lds(
      (const __attribute__((address_space(1))) unsigned int*)gsrc,
      (__attribute__((address_space(3))) unsigned int*)ldst, 16, 0, 0);
}

// ---------------------------------------------------------------------------
// Weight prep: WqT/WkT/WvT/WoT = W^T bf16; projcat[512][1024]:
// rows 0-255 = projk^T, rows 256-511 = projv^T.
// ---------------------------------------------------------------------------
__global__ __launch_bounds__(256) void transcvt_all(
    const float* __restrict__ w0, const float* __restrict__ w1,
    const float* __restrict__ w2, const float* __restrict__ w3,
    const float* __restrict__ p0, const float* __restrict__ p1,
    unsigned short* __restrict__ d0, unsigned short* __restrict__ d1,
    unsigned short* __restrict__ d2, unsigned short* __restrict__ d3,
    unsigned short* __restrict__ e0, unsigned short* __restrict__ e1) {
  const int m = blockIdx.y;
  const float* src = m==0?w0:m==1?w1:m==2?w2:m==3?w3:m==4?p0:p1;
  unsigned short* dst = m==0?d0:m==1?d1:m==2?d2:m==3?d3:m==4?e0:e1;
  const int R = (m < 4) ? 512 : 1024;
  const int logC = (m < 4) ? 9 : 8;
  int idx = blockIdx.x * 256 + threadIdx.x;
  int r = idx >> logC, c = idx & ((1 << logC) - 1);
  dst[(size_t)c * R + r] = f2bf(src[idx]);
}

// ---------------------------------------------------------------------------
// xf = transpose(x) + pos ; y = relu(LN(xf)) -> y [B*N][C] and yT [B][C][N]
// ---------------------------------------------------------------------------
__global__ __launch_bounds__(256) void ln_relu_kernel(
    const float* __restrict__ x, const float* __restrict__ pos,
    const float* __restrict__ g, const float* __restrict__ bta,
    unsigned short* __restrict__ y, unsigned short* __restrict__ yT) {
  __shared__ float tile[16][516];
  __shared__ float smu[16], srs[16];
  const int b = blockIdx.y, n0 = blockIdx.x * 16;
  const int tid = threadIdx.x;
  const float* xb = x + (size_t)b * CC * NN;

  #pragma unroll
  for (int i = 0; i < 32; ++i) {
    int e = i * 256 + tid;
    int c = e >> 4, nl = e & 15;
    tile[nl][c] = xb[(size_t)c * NN + n0 + nl];
  }
  __syncthreads();

  const int r = tid >> 4, l16 = tid & 15;
  float s = 0.f, s2 = 0.f;
  #pragma unroll
  for (int i = 0; i < 32; ++i) {
    int c = l16 + i * 16;
    float v = tile[r][c] + pos[(size_t)(n0 + r) * CC + c];
    s += v; s2 += v * v;
  }
  #pragma unroll
  for (int d = 1; d < 16; d <<= 1) { s += __shfl_xor(s, d); s2 += __shfl_xor(s2, d); }
  if (l16 == 0) {
    float mu = s * (1.f / 512.f);
    float var = s2 * (1.f / 512.f) - mu * mu;
    smu[r] = mu;
    srs[r] = rsqrtf(var + 1e-5f);
  }
  __syncthreads();

  unsigned short* yb = y + ((size_t)b * NN + n0) * CC;
  #pragma unroll
  for (int rr = 0; rr < 16; ++rr) {
    float mu = smu[rr], rs = srs[rr];
    #pragma unroll
    for (int c = tid; c < CC; c += 256) {
      float v = tile[rr][c] + pos[(size_t)(n0 + rr) * CC + c];
      float o = (v - mu) * rs * g[c] + bta[c];
      o = o > 0.f ? o : 0.f;
      yb[(size_t)rr * CC + c] = f2bf(o);
      tile[rr][c] = o;                 // keep for transposed store
    }
  }
  __syncthreads();

  unsigned short* ytb = yT + (size_t)b * CC * NN + n0;
  #pragma unroll
  for (int cc = tid; cc < CC; cc += 256) {
    unsigned int pk8[8];
    #pragma unroll
    for (int p = 0; p < 8; ++p)
      pk8[p] = (unsigned int)f2bf(tile[2 * p][cc]) |
               ((unsigned int)f2bf(tile[2 * p + 1][cc]) << 16);
    *reinterpret_cast<uint4*>(&ytb[(size_t)cc * NN])     = *reinterpret_cast<uint4*>(&pk8[0]);
    *reinterpret_cast<uint4*>(&ytb[(size_t)cc * NN + 8]) = *reinterpret_cast<uint4*>(&pk8[4]);
  }
}

// ---------------------------------------------------------------------------
// TN GEMM: C[M,N] = A[M,K]*Bt[N,K]^T. 128x128 tile, BK=64, double-buffered
// LDS with prefetch-before-compute (one barrier per K-step), XOR-swizzled
// (chunk ^= row&7, pre-swizzled global source + swizzled b128 reads).
// MODE 0: bf16 row-major; MODE 1: bf16 transposed; MODE 2: f32 fused epilogue
// ---------------------------------------------------------------------------
template <int MODE>
__global__ __launch_bounds__(256) void gemm_tn(
    const unsigned short* __restrict__ A, int lda, long long strideA,
    const unsigned short* __restrict__ Bt, int ldb, long long strideB,
    unsigned short* __restrict__ Cb, long long strideC,
    int Nn, int Kk, int TB,
    const float* __restrict__ xres, const float* __restrict__ posres,
    const float* __restrict__ bias, float* __restrict__ outF) {
  __shared__ __align__(16) unsigned short aL[2][128 * 64];
  __shared__ __align__(16) unsigned short bL[2][128 * 64];
  const int mb = blockIdx.x * 128, nb = blockIdx.y * 128, zb = blockIdx.z;
  A  += (size_t)strideA * zb;
  Bt += (size_t)strideB * zb;
  if (MODE == 0 || MODE == 1) Cb += (size_t)strideC * zb;
  const int tid  = threadIdx.x;
  const int lane = tid & 63;
  const int wave = tid >> 6;
  const int wm = (wave >> 1) * 64, wn = (wave & 1) * 64;
  const int sr = lane >> 3;          // row within 8-row staging group
  const int scw = lane & 7;          // linear 16B chunk this lane fills
  f32x4 acc[4][4] = {};

  auto stage = [&](int buf, int k0) {
    #pragma unroll
    for (int i = 0; i < 4; ++i) {
      int row = wave * 32 + i * 8 + sr;
      int ca = scw ^ (row & 7);      // global chunk that belongs in linear slot scw
      gload16(&A [(size_t)(mb + row) * lda + k0 + ca * 8], &aL[buf][(wave * 32 + i * 8) * 64]);
      gload16(&Bt[(size_t)(nb + row) * ldb + k0 + ca * 8], &bL[buf][(wave * 32 + i * 8) * 64]);
    }
  };

  const int nt = Kk >> 6;
  stage(0, 0);
  __syncthreads();

  for (int t = 0; t < nt; ++t) {
    const int buf = t & 1;
    if (t + 1 < nt) stage(buf ^ 1, (t + 1) << 6);

    bf16x8 af[2][4], bfv[2][4];
    #pragma unroll
    for (int ks = 0; ks < 2; ++ks)
      #pragma unroll
      for (int i = 0; i < 4; ++i) {
        int ra = wm + i * 16 + (lane & 15);
        int rb = wn + i * 16 + (lane & 15);
        int kc = ks * 4 + (lane >> 4);
        af[ks][i]  = *reinterpret_cast<const bf16x8*>(&aL[buf][ra * 64 + (kc ^ (ra & 7)) * 8]);
        bfv[ks][i] = *reinterpret_cast<const bf16x8*>(&bL[buf][rb * 64 + (kc ^ (rb & 7)) * 8]);
      }
    #pragma unroll
    for (int ks = 0; ks < 2; ++ks)
      #pragma unroll
      for (int i = 0; i < 4; ++i)
        #pragma unroll
        for (int j = 0; j < 4; ++j)
          acc[i][j] = __builtin_amdgcn_mfma_f32_16x16x32_bf16(af[ks][i], bfv[ks][j], acc[i][j], 0, 0, 0);
    __syncthreads();
  }

  #pragma unroll
  for (int i = 0; i < 4; ++i) {
    const int r0 = mb + wm + i * 16 + ((lane >> 4) << 2);
    #pragma unroll
    for (int j = 0; j < 4; ++j) {
      const int col = nb + wn + j * 16 + (lane & 15);
      if (MODE == 0) {
        #pragma unroll
        for (int t = 0; t < 4; ++t)
          Cb[(size_t)(r0 + t) * Nn + col] = f2bf(acc[i][j][t]);
      } else if (MODE == 1) {
        unsigned int lo = (unsigned int)f2bf(acc[i][j][0]) | ((unsigned int)f2bf(acc[i][j][1]) << 16);
        unsigned int hi = (unsigned int)f2bf(acc[i][j][2]) | ((unsigned int)f2bf(acc[i][j][3]) << 16);
        size_t addr = (size_t)col * TB + (r0 % TB);
        uint2 u; u.x = lo; u.y = hi;
        *reinterpret_cast<uint2*>(&Cb[addr]) = u;
      } else {
        const int bb = r0 >> 10, t0 = r0 & 1023;
        const size_t base = ((size_t)bb * CC + col) * NN + t0;
        float4 xv = *reinterpret_cast<const float4*>(&xres[base]);
        float bcol = bias[col];
        float4 ov;
        ov.x = acc[i][j][0] + bcol + xv.x + posres[(size_t)(t0 + 0) * CC + col];
        ov.y = acc[i][j][1] + bcol + xv.y + posres[(size_t)(t0 + 1) * CC + col];
        ov.z = acc[i][j][2] + bcol + xv.z + posres[(size_t)(t0 + 2) * CC + col];
        ov.w = acc[i][j][3] + bcol + xv.w + posres[(size_t)(t0 + 3) * CC + col];
        *reinterpret_cast<float4*>(&outF[base]) = ov;
      }
    }
  }
}

// ---------------------------------------------------------------------------
// Attention, 32x32x16 MFMA, swapped QK^T, in-register softmax.
// ---------------------------------------------------------------------------
__global__ __launch_bounds__(256, 2) void attn_kernel(
    const unsigned short* __restrict__ q,    // [B*N][C]
    const unsigned short* __restrict__ kB,   // [B][KR][C]
    const unsigned short* __restrict__ vT,   // [B][C][KR]
    unsigned short* __restrict__ O) {        // [B*N][C]
  __shared__ __align__(16) unsigned short smem[32768]; // K [256][64] @0, V [64][256] @16384
  const int wgid = blockIdx.x;
  const int grp  = wgid & 255;
  const int tg   = wgid >> 8;
  const int h = grp & 7, b = grp >> 3;
  const int wave = threadIdx.x >> 6, lane = threadIdx.x & 63;
  const int t32 = lane & 31, g2 = lane >> 5;
  const int tokb = tg * 128 + wave * 32;

  const unsigned short* qp = q + ((size_t)(b * NN + tokb + t32)) * CC + h * DHH + g2 * 8;
  bf16x8 qf[4];
  #pragma unroll
  for (int st = 0; st < 4; ++st)
    qf[st] = *reinterpret_cast<const bf16x8*>(qp + (size_t)st * 16);

  {
    const unsigned short* kb = kB + ((size_t)b * KR) * CC + h * DHH;
    const int r0w = wave * 64;
    #pragma unroll
    for (int i = 0; i < 8; ++i) {
      int row = r0w + i * 8 + (lane >> 3);
      int sc  = (lane & 7) ^ (row & 7);
      gload16(kb + (size_t)row * CC + sc * 8, &smem[(r0w + i * 8) * 64]);
    }
    const unsigned short* vb = vT + ((size_t)b * CC + h * DHH) * KR;
    const int v0w = wave * 16;
    #pragma unroll
    for (int i = 0; i < 8; ++i) {
      int row = v0w + i * 2 + (lane >> 5);
      int sc  = (lane & 31) ^ (row & 7);
      gload16(vb + (size_t)row * KR + sc * 8, &smem[16384 + (v0w + i * 2) * 256]);
    }
  }
  __syncthreads();

  f32x16 s8[8] = {};
  #pragma unroll
  for (int t8 = 0; t8 < 8; ++t8) {
    const int row = t8 * 32 + t32;
    #pragma unroll
    for (int st = 0; st < 4; ++st) {
      int ch = (2 * st + g2) ^ (row & 7);
      bf16x8 kf = *reinterpret_cast<const bf16x8*>(&smem[row * 64 + ch * 8]);
      s8[t8] = __builtin_amdgcn_mfma_f32_32x32x16_bf16(kf, qf[st], s8[t8], 0, 0, 0);
    }
  }

  float m = -1e30f;
  #pragma unroll
  for (int t8 = 0; t8 < 8; ++t8)
    #pragma unroll
    for (int r = 0; r < 16; ++r) m = fmaxf(m, s8[t8][r]);
  m = fmaxf(m, __shfl_xor(m, 32));
  const float cexp = 0.125f * 1.44269504088896f;
  float ls = 0.f;
  #pragma unroll
  for (int t8 = 0; t8 < 8; ++t8)
    #pragma unroll
    for (int r = 0; r < 16; ++r) {
      float p = __builtin_amdgcn_exp2f((s8[t8][r] - m) * cexp);
      s8[t8][r] = p;
      ls += p;
    }
  ls += __shfl_xor(ls, 32);
  float rinv = __builtin_amdgcn_rcpf(ls);

  f32x16 o0 = {}, o1 = {};
  #pragma unroll
  for (int t8 = 0; t8 < 8; ++t8) {
    unsigned int pkd[8];
    #pragma unroll
    for (int qq = 0; qq < 4; ++qq) {
      pkd[qq * 2 + 0] = pknat(s8[t8][4 * qq + 0], s8[t8][4 * qq + 1]);
      pkd[qq * 2 + 1] = pknat(s8[t8][4 * qq + 2], s8[t8][4 * qq + 3]);
    }
    #pragma unroll
    for (int a = 0; a < 2; ++a) {
      const int ks = t8 * 2 + a;
      unsigned int xe0 = pkd[4 * a + 0], xe1 = pkd[4 * a + 1];
      unsigned int xo0 = pkd[4 * a + 2], xo1 = pkd[4 * a + 3];
      unsigned int d0 = g2 ? __shfl_xor(xo0, 32) : xe0;
      unsigned int d1 = g2 ? __shfl_xor(xo1, 32) : xe1;
      unsigned int d2 = g2 ? xo0 : __shfl_xor(xe0, 32);
      unsigned int d3 = g2 ? xo1 : __shfl_xor(xe1, 32);
      u32x4 pv_ = {d0, d1, d2, d3};
      bf16x8 pa = __builtin_bit_cast(bf16x8, pv_);
      #pragma unroll
      for (int dt = 0; dt < 2; ++dt) {
        int row = dt * 32 + t32;
        int ch = (2 * ks + g2) ^ (row & 7);
        bf16x8 bv = *reinterpret_cast<const bf16x8*>(&smem[16384 + row * 256 + ch * 8]);
        if (dt == 0) o0 = __builtin_amdgcn_mfma_f32_32x32x16_bf16(pa, bv, o0, 0, 0, 0);
        else         o1 = __builtin_amdgcn_mfma_f32_32x32x16_bf16(pa, bv, o1, 0, 0, 0);
      }
    }
  }

  unsigned short* Ob = O + ((size_t)(b * NN + tokb)) * CC + h * DHH;
  #pragma unroll
  for (int r = 0; r < 16; ++r) {
    int tl = (r & 3) + 8 * (r >> 2) + 4 * g2;
    float rs = __shfl(rinv, tl);
    Ob[(size_t)tl * CC + t32]      = f2bf(o0[r] * rs);
    Ob[(size_t)tl * CC + 32 + t32] = f2bf(o1[r] * rs);
  }
}

// ---------------------------------------------------------------------------
extern "C" void kernel_launch(void* const* d_in, const int* in_sizes, int n_in,
                              void* d_out, int out_size, void* d_ws, size_t ws_size,
                              hipStream_t stream) {
  const float* x    = (const float*)d_in[0];
  const float* pos  = (const float*)d_in[1];
  const float* ln_g = (const float*)d_in[2];
  const float* ln_b = (const float*)d_in[3];
  const float* Wq   = (const float*)d_in[4];
  const float* Wk   = (const float*)d_in[5];
  const float* Wv   = (const float*)d_in[6];
  const float* pk   = (const float*)d_in[7];
  const float* pv   = (const float*)d_in[8];
  const float* Wo   = (const float*)d_in[9];
  const float* bo   = (const float*)d_in[10];
  float* out = (float*)d_out;

  unsigned short* ws = (unsigned short*)d_ws;
  size_t off = 0;
  auto alloc = [&](size_t elems) { unsigned short* p = ws + off; off += elems; return p; };
  unsigned short* WqT     = alloc(512 * 512);
  unsigned short* WkT     = alloc(512 * 512);
  unsigned short* WvT     = alloc(512 * 512);
  unsigned short* WoT     = alloc(512 * 512);
  unsigned short* projcat = alloc((size_t)512 * 1024);   // [512][1024]
  unsigned short* yB      = alloc((size_t)32768 * 512);
  unsigned short* yT      = alloc((size_t)32 * 512 * 1024);
  unsigned short* qB      = alloc((size_t)32768 * 512);
  unsigned short* zB      = alloc((size_t)32 * 512 * 512); // rows 0-255 zk, 256-511 zv
  unsigned short* kBuf    = alloc((size_t)32 * 256 * 512);
  unsigned short* vTB     = alloc((size_t)32 * 512 * 256);
  unsigned short* OB      = alloc((size_t)32768 * 512);

  transcvt_all<<<dim3(1024, 6), 256, 0, stream>>>(
      Wq, Wk, Wv, Wo, pk, pv,
      WqT, WkT, WvT, WoT, projcat, projcat + (size_t)256 * 1024);

  ln_relu_kernel<<<dim3(64, 32), 256, 0, stream>>>(x, pos, ln_g, ln_b, yB, yT);

  // q = y @ Wq
  gemm_tn<0><<<dim3(256, 4), 256, 0, stream>>>(
      yB, 512, 0, WqT, 512, 0, qB, 0, 512, 512, 0, nullptr, nullptr, nullptr, nullptr);

  // z = projcat @ y_b  (batched; zk rows 0-255, zv rows 256-511)
  gemm_tn<0><<<dim3(4, 4, 32), 256, 0, stream>>>(
      projcat, 1024, 0, yT, 1024, (long long)512 * 1024, zB, (long long)512 * 512,
      512, 1024, 0, nullptr, nullptr, nullptr, nullptr);

  // k_ = zk @ Wk -> [b][kk][c]
  gemm_tn<0><<<dim3(2, 4, 32), 256, 0, stream>>>(
      zB, 512, (long long)512 * 512, WkT, 512, 0, kBuf, (long long)256 * 512,
      512, 512, 0, nullptr, nullptr, nullptr, nullptr);

  // v_ = zv @ Wv -> transposed [b][c][kk]
  gemm_tn<1><<<dim3(2, 4, 32), 256, 0, stream>>>(
      zB + (size_t)256 * 512, 512, (long long)512 * 512, WvT, 512, 0,
      vTB, (long long)512 * 256, 512, 512, 256, nullptr, nullptr, nullptr, nullptr);

  attn_kernel<<<dim3(2048, 1, 1), 256, 0, stream>>>(qB, kBuf, vTB, OB);

  // out = O @ Wo + bo + (x + pos), stored [b][c][tok] f32
  gemm_tn<2><<<dim3(256, 4), 256, 0, stream>>>(
      OB, 512, 0, WoT, 512, 0, nullptr, 0, 512, 512, 0, x, pos, bo, out);
}